// Round 1
// baseline (316.181 us; speedup 1.0000x reference)
//
#include <hip/hip_runtime.h>
#include <hip/hip_bf16.h>

// Problem constants
#define BB   4096
#define INW  1024
#define HH   1024
#define KIN  2048      // IN + H
#define NG   5120      // 3H + 2H
#define KH   32        // inner hidden

typedef __bf16 bf16;
typedef __bf16 bf16x4 __attribute__((ext_vector_type(4)));
typedef __bf16 bf16x8 __attribute__((ext_vector_type(8)));
typedef float  floatx4 __attribute__((ext_vector_type(4)));

#define GLD16(gp, lp)                                                          \
  __builtin_amdgcn_global_load_lds(                                            \
      (__attribute__((address_space(1))) const void*)(gp),                     \
      (__attribute__((address_space(3))) void*)(lp), 16, 0, 0)

// ---------------------------------------------------------------------------
// 1a. combined = concat([x, h_prev], axis=1) cast to bf16, [B, KIN]
// ---------------------------------------------------------------------------
__global__ __launch_bounds__(256) void build_combined(
    const float* __restrict__ x, const float* __restrict__ h,
    bf16* __restrict__ out) {
  int idx = blockIdx.x * 256 + threadIdx.x;   // one thread = 4 elements
  int e = idx * 4;
  int b = e >> 11;          // / KIN
  int c = e & (KIN - 1);
  const float* src = (c < INW) ? (x + b * INW + c) : (h + b * HH + (c - INW));
  float4 v = *(const float4*)src;
  bf16x4 o;
  o[0] = (bf16)v.x; o[1] = (bf16)v.y; o[2] = (bf16)v.z; o[3] = (bf16)v.w;
  *(bf16x4*)(out + e) = o;
}

// ---------------------------------------------------------------------------
// 1b. generic fp32 -> bf16 cast (for Wg, Wc into one [NG, KIN] buffer)
// ---------------------------------------------------------------------------
__global__ __launch_bounds__(256) void cvt_bf16(
    const float* __restrict__ in, bf16* __restrict__ out, int n4) {
  int i = blockIdx.x * 256 + threadIdx.x;
  if (i < n4) {
    float4 v = ((const float4*)in)[i];
    bf16x4 o;
    o[0] = (bf16)v.x; o[1] = (bf16)v.y; o[2] = (bf16)v.z; o[3] = (bf16)v.w;
    ((bf16x4*)out)[i] = o;
  }
}

// ---------------------------------------------------------------------------
// 2. GEMM: C[M,N] = A[M,K] * Bm[N,K]^T   (M=4096, N=5120, K=2048)
//    m97 structure: 128x128 block tile, BK=64, 256 threads (4 waves 2x2),
//    global_load_lds width-16 staging, mfma_f32_16x16x32_bf16.
// ---------------------------------------------------------------------------
__global__ __launch_bounds__(256) void gemm_bt(
    const bf16* __restrict__ A, const bf16* __restrict__ Bm,
    float* __restrict__ C) {
  __shared__ bf16 As[128 * 64];
  __shared__ bf16 Bs[128 * 64];

  const int tid  = threadIdx.x;
  const int wave = tid >> 6;
  const int lane = tid & 63;
  const int m0 = blockIdx.x * 128;
  const int n0 = blockIdx.y * 128;
  const int wm = (wave >> 1) * 64;   // wave row origin in tile
  const int wn = (wave & 1) * 64;    // wave col origin in tile
  const int lr = lane & 15;          // row within 16x16 fragment
  const int lk = (lane >> 4) * 8;    // k-offset within 32

  floatx4 acc[4][4] = {};

  for (int kt = 0; kt < KIN / 64; ++kt) {
    const int k0 = kt * 64;
    __syncthreads();  // previous compute must be done before LDS overwrite
#pragma unroll
    for (int j = 0; j < 4; ++j) {
      int q = j * 256 + tid;              // 16B chunk id, 1024 chunks/tile
      int row = q >> 3;
      int ck  = (q & 7) * 8;
      GLD16(A + (size_t)(m0 + row) * KIN + k0 + ck,
            As + (size_t)(j * 256 + wave * 64) * 8);
      GLD16(Bm + (size_t)(n0 + row) * KIN + k0 + ck,
            Bs + (size_t)(j * 256 + wave * 64) * 8);
    }
    __syncthreads();  // compiler emits vmcnt(0) drain before barrier

#pragma unroll
    for (int ks = 0; ks < 2; ++ks) {
      bf16x8 af[4], bf[4];
#pragma unroll
      for (int mi = 0; mi < 4; ++mi)
        af[mi] = *(const bf16x8*)&As[(wm + mi * 16 + lr) * 64 + ks * 32 + lk];
#pragma unroll
      for (int ni = 0; ni < 4; ++ni)
        bf[ni] = *(const bf16x8*)&Bs[(wn + ni * 16 + lr) * 64 + ks * 32 + lk];
#pragma unroll
      for (int mi = 0; mi < 4; ++mi)
#pragma unroll
        for (int ni = 0; ni < 4; ++ni)
          acc[mi][ni] = __builtin_amdgcn_mfma_f32_16x16x32_bf16(
              af[mi], bf[ni], acc[mi][ni], 0, 0, 0);
    }
  }

  // Epilogue: C/D layout col = lane&15, row = (lane>>4)*4 + reg
  const int quad = lane >> 4;
#pragma unroll
  for (int mi = 0; mi < 4; ++mi)
#pragma unroll
    for (int ni = 0; ni < 4; ++ni) {
      size_t base = (size_t)(m0 + wm + mi * 16 + quad * 4) * NG
                    + (n0 + wn + ni * 16 + lr);
#pragma unroll
      for (int r = 0; r < 4; ++r)
        C[base + (size_t)r * NG] = acc[mi][ni][r];
    }
}

// ---------------------------------------------------------------------------
// 3. Fused epilogue: gates + inner MLP + cell update
// ---------------------------------------------------------------------------
__global__ __launch_bounds__(256) void epilogue(
    const float* __restrict__ G, const float* __restrict__ c_prev,
    const float* __restrict__ bg, const float* __restrict__ bc,
    const float* __restrict__ W1, const float* __restrict__ b1,
    const float* __restrict__ W2, const float* __restrict__ b2,
    float* __restrict__ h_next, float* __restrict__ c_next) {
  int idx = blockIdx.x * 256 + threadIdx.x;   // one per (b,h)
  int b = idx >> 10;
  int h = idx & (HH - 1);
  const float* Gr = G + (size_t)b * NG;

  float gi = Gr[h]            + bg[h];
  float gf = Gr[HH + h]       + bg[HH + h];
  float go = Gr[2 * HH + h]   + bg[2 * HH + h];
  float p0 = Gr[3 * HH + 2 * h]     + bc[2 * h];
  float p1 = Gr[3 * HH + 2 * h + 1] + bc[2 * h + 1];

  float g = b2[0];
#pragma unroll
  for (int k = 0; k < KH; ++k) {
    float hv = fmaf(p0, W1[2 * k], fmaf(p1, W1[2 * k + 1], b1[k]));
    hv = fmaxf(hv, 0.0f);
    g = fmaf(hv, W2[k], g);
  }

  float si = 1.0f / (1.0f + __expf(-gi));
  float sf = 1.0f / (1.0f + __expf(-gf));
  float so = 1.0f / (1.0f + __expf(-go));

  float cn = sf * c_prev[idx] + si * g;
  float hn = so * tanhf(cn);
  h_next[idx] = hn;
  c_next[idx] = cn;
}

// ---------------------------------------------------------------------------
extern "C" void kernel_launch(void* const* d_in, const int* in_sizes, int n_in,
                              void* d_out, int out_size, void* d_ws, size_t ws_size,
                              hipStream_t stream) {
  const float* x      = (const float*)d_in[0];
  const float* h_prev = (const float*)d_in[1];
  const float* c_prev = (const float*)d_in[2];
  const float* Wg     = (const float*)d_in[3];
  const float* bg     = (const float*)d_in[4];
  const float* Wc     = (const float*)d_in[5];
  const float* bc     = (const float*)d_in[6];
  const float* W1     = (const float*)d_in[7];
  const float* b1     = (const float*)d_in[8];
  const float* W2     = (const float*)d_in[9];
  const float* b2     = (const float*)d_in[10];
  float* out = (float*)d_out;

  // workspace layout
  char* ws = (char*)d_ws;
  bf16*  comb = (bf16*)ws;                                    // 16 MB
  bf16*  Wb   = (bf16*)(ws + (size_t)BB * KIN * 2);           // 20 MB
  float* G    = (float*)(ws + (size_t)BB * KIN * 2
                            + (size_t)NG * KIN * 2);          // 80 MB

  // 1. casts
  build_combined<<<(BB * KIN / 4) / 256, 256, 0, stream>>>(x, h_prev, comb);
  cvt_bf16<<<(3 * HH * KIN / 4) / 256, 256, 0, stream>>>(Wg, Wb, 3 * HH * KIN / 4);
  cvt_bf16<<<(2 * HH * KIN / 4) / 256, 256, 0, stream>>>(
      Wc, Wb + (size_t)3 * HH * KIN, 2 * HH * KIN / 4);

  // 2. GEMM
  dim3 grid(BB / 128, NG / 128);
  gemm_bt<<<grid, 256, 0, stream>>>(comb, Wb, G);

  // 3. epilogue
  epilogue<<<(BB * HH) / 256, 256, 0, stream>>>(
      G, c_prev, bg, bc, W1, b1, W2, b2, out, out + (size_t)BB * HH);
}

// Round 2
// 276.894 us; speedup vs baseline: 1.1419x; 1.1419x over previous
//
#include <hip/hip_runtime.h>
#include <hip/hip_bf16.h>

// Problem constants
#define BB   4096
#define INW  1024
#define HH   1024
#define KIN  2048      // IN + H
#define NG   5120      // 3H + 2H
#define KH   32        // inner hidden

typedef __bf16 bf16;
typedef __bf16 bf16x4 __attribute__((ext_vector_type(4)));
typedef __bf16 bf16x8 __attribute__((ext_vector_type(8)));
typedef float  floatx4 __attribute__((ext_vector_type(4)));

#define GLD16(gp, lp)                                                          \
  __builtin_amdgcn_global_load_lds(                                            \
      (__attribute__((address_space(1))) const void*)(gp),                     \
      (__attribute__((address_space(3))) void*)(lp), 16, 0, 0)

// ---------------------------------------------------------------------------
// 1. prep: concat+cast x|h_prev -> comb bf16, and cast Wg,Wc -> Wb bf16
// ---------------------------------------------------------------------------
#define NC4  (BB * KIN / 4)        // 2097152 float4 groups for comb
#define NWG4 (3 * HH * KIN / 4)    // 1572864 for Wg
#define NWC4 (2 * HH * KIN / 4)    // 1048576 for Wc

__global__ __launch_bounds__(256) void prep(
    const float* __restrict__ x, const float* __restrict__ h,
    const float* __restrict__ Wg, const float* __restrict__ Wc,
    bf16* __restrict__ comb, bf16* __restrict__ Wb) {
  int i = blockIdx.x * 256 + threadIdx.x;   // one float4 group
  const float* src;
  bf16* dst;
  if (i < NC4) {
    int e = i * 4;
    int b = e >> 11;          // / KIN
    int c = e & (KIN - 1);
    src = (c < INW) ? (x + (size_t)b * INW + c) : (h + (size_t)b * HH + (c - INW));
    dst = comb + e;
  } else if (i < NC4 + NWG4) {
    int e = (i - NC4) * 4;
    src = Wg + e;
    dst = Wb + e;
  } else {
    int e = (i - NC4 - NWG4) * 4;
    src = Wc + e;
    dst = Wb + (size_t)3 * HH * KIN + e;
  }
  float4 v = *(const float4*)src;
  bf16x4 o;
  o[0] = (bf16)v.x; o[1] = (bf16)v.y; o[2] = (bf16)v.z; o[3] = (bf16)v.w;
  *(bf16x4*)dst = o;
}

// ---------------------------------------------------------------------------
// 2. GEMM: G[M,N] = A[M,K] * Bm[N,K]^T   (M=4096, N=5120, K=2048), bf16 out.
//    m97 structure + XOR-swizzled LDS chunks to kill bank conflicts:
//    chunk (row, c) lives at slot row*8 + (c ^ (row&7)); legal because
//    global_load_lds pins the LDS side (base+lane*16) but the global side
//    is a free per-lane address.
// ---------------------------------------------------------------------------
__global__ __launch_bounds__(256) void gemm_bt(
    const bf16* __restrict__ A, const bf16* __restrict__ Bm,
    bf16* __restrict__ C) {
  __shared__ bf16 As[128 * 64];
  __shared__ bf16 Bs[128 * 64];

  const int tid  = threadIdx.x;
  const int wave = tid >> 6;
  const int lane = tid & 63;
  const int m0 = blockIdx.x * 128;
  const int n0 = blockIdx.y * 128;
  const int wm = (wave >> 1) * 64;   // wave row origin in tile
  const int wn = (wave & 1) * 64;    // wave col origin in tile
  const int lr = lane & 15;          // row within 16x16 fragment
  const int qd = lane >> 4;          // k-chunk quad index (0..3)
  const int sw = lr & 7;             // read-side swizzle key (row&7 == lr&7)

  floatx4 acc[4][4] = {};

  for (int kt = 0; kt < KIN / 64; ++kt) {
    const int k0 = kt * 64;
    __syncthreads();  // previous compute must be done before LDS overwrite
#pragma unroll
    for (int j = 0; j < 4; ++j) {
      int q   = j * 256 + tid;            // LDS 16B slot id, 1024 slots/tile
      int row = q >> 3;
      int c   = (q & 7) ^ (row & 7);      // global chunk for this slot (XOR swizzle)
      GLD16(A + (size_t)(m0 + row) * KIN + k0 + c * 8,
            As + (size_t)(j * 256 + wave * 64) * 8);
      GLD16(Bm + (size_t)(n0 + row) * KIN + k0 + c * 8,
            Bs + (size_t)(j * 256 + wave * 64) * 8);
    }
    __syncthreads();

#pragma unroll
    for (int ks = 0; ks < 2; ++ks) {
      bf16x8 af[4], bfr[4];
#pragma unroll
      for (int mi = 0; mi < 4; ++mi)
        af[mi] = *(const bf16x8*)
            &As[(((wm + mi * 16 + lr) << 3) + ((ks * 4 + qd) ^ sw)) << 3];
#pragma unroll
      for (int ni = 0; ni < 4; ++ni)
        bfr[ni] = *(const bf16x8*)
            &Bs[(((wn + ni * 16 + lr) << 3) + ((ks * 4 + qd) ^ sw)) << 3];
#pragma unroll
      for (int mi = 0; mi < 4; ++mi)
#pragma unroll
        for (int ni = 0; ni < 4; ++ni)
          acc[mi][ni] = __builtin_amdgcn_mfma_f32_16x16x32_bf16(
              af[mi], bfr[ni], acc[mi][ni], 0, 0, 0);
    }
  }

  // Epilogue: C/D layout col = lane&15, row = (lane>>4)*4 + reg. bf16 store.
#pragma unroll
  for (int mi = 0; mi < 4; ++mi)
#pragma unroll
    for (int ni = 0; ni < 4; ++ni) {
      size_t base = (size_t)(m0 + wm + mi * 16 + qd * 4) * NG
                    + (n0 + wn + ni * 16 + lr);
#pragma unroll
      for (int r = 0; r < 4; ++r)
        C[base + (size_t)r * NG] = (bf16)acc[mi][ni][r];
    }
}

// ---------------------------------------------------------------------------
// 3. Fused epilogue: gates + inner MLP + cell update (reads bf16 G)
// ---------------------------------------------------------------------------
__global__ __launch_bounds__(256) void epilogue(
    const bf16* __restrict__ G, const float* __restrict__ c_prev,
    const float* __restrict__ bg, const float* __restrict__ bc,
    const float* __restrict__ W1, const float* __restrict__ b1,
    const float* __restrict__ W2, const float* __restrict__ b2,
    float* __restrict__ h_next, float* __restrict__ c_next) {
  int idx = blockIdx.x * 256 + threadIdx.x;   // one per (b,h)
  int b = idx >> 10;
  int h = idx & (HH - 1);
  const bf16* Gr = G + (size_t)b * NG;

  float gi = (float)Gr[h]          + bg[h];
  float gf = (float)Gr[HH + h]     + bg[HH + h];
  float go = (float)Gr[2 * HH + h] + bg[2 * HH + h];
  float p0 = (float)Gr[3 * HH + 2 * h]     + bc[2 * h];
  float p1 = (float)Gr[3 * HH + 2 * h + 1] + bc[2 * h + 1];

  float g = b2[0];
#pragma unroll
  for (int k = 0; k < KH; ++k) {
    float hv = fmaf(p0, W1[2 * k], fmaf(p1, W1[2 * k + 1], b1[k]));
    hv = fmaxf(hv, 0.0f);
    g = fmaf(hv, W2[k], g);
  }

  float si = 1.0f / (1.0f + __expf(-gi));
  float sf = 1.0f / (1.0f + __expf(-gf));
  float so = 1.0f / (1.0f + __expf(-go));

  float cn = sf * c_prev[idx] + si * g;
  float hn = so * tanhf(cn);
  h_next[idx] = hn;
  c_next[idx] = cn;
}

// ---------------------------------------------------------------------------
extern "C" void kernel_launch(void* const* d_in, const int* in_sizes, int n_in,
                              void* d_out, int out_size, void* d_ws, size_t ws_size,
                              hipStream_t stream) {
  const float* x      = (const float*)d_in[0];
  const float* h_prev = (const float*)d_in[1];
  const float* c_prev = (const float*)d_in[2];
  const float* Wg     = (const float*)d_in[3];
  const float* bg     = (const float*)d_in[4];
  const float* Wc     = (const float*)d_in[5];
  const float* bc     = (const float*)d_in[6];
  const float* W1     = (const float*)d_in[7];
  const float* b1     = (const float*)d_in[8];
  const float* W2     = (const float*)d_in[9];
  const float* b2     = (const float*)d_in[10];
  float* out = (float*)d_out;

  // workspace layout
  char* ws = (char*)d_ws;
  bf16* comb = (bf16*)ws;                                    // 16 MB
  bf16* Wb   = (bf16*)(ws + (size_t)BB * KIN * 2);           // 20 MB
  bf16* G    = (bf16*)(ws + (size_t)BB * KIN * 2
                          + (size_t)NG * KIN * 2);           // 40 MB

  // 1. prep (concat + casts, one kernel)
  prep<<<(NC4 + NWG4 + NWC4) / 256, 256, 0, stream>>>(x, h_prev, Wg, Wc, comb, Wb);

  // 2. GEMM
  dim3 grid(BB / 128, NG / 128);
  gemm_bt<<<grid, 256, 0, stream>>>(comb, Wb, G);

  // 3. epilogue
  epilogue<<<(BB * HH) / 256, 256, 0, stream>>>(
      G, c_prev, bg, bc, W1, b1, W2, b2, out, out + (size_t)BB * HH);
}